// Round 17
// baseline (204.177 us; speedup 1.0000x reference)
//
#include <hip/hip_runtime.h>
#include <hip/hip_bf16.h>
#include <math.h>

#define PI_F  3.14159265358979323846f
#define LOG2E 1.44269504088896340736f

typedef __attribute__((ext_vector_type(8))) short          bf16x8;
typedef __attribute__((ext_vector_type(8))) unsigned short ushort8;
typedef __attribute__((ext_vector_type(4))) float          f32x4;

__device__ __forceinline__ unsigned short f2bf(float f) {
  union { float f; unsigned u; } v; v.f = f;
  unsigned r = v.u + 0x7fffu + ((v.u >> 16) & 1u);
  return (unsigned short)(r >> 16);
}

__device__ __forceinline__ unsigned short f2bf_hw(float f) {
  __hip_bfloat16 h = __float2bfloat16(f);
  return *reinterpret_cast<unsigned short*>(&h);
}

#define GLOAD16(g, l)                                                         \
  __builtin_amdgcn_global_load_lds(                                           \
      (const __attribute__((address_space(1))) void*)(g),                     \
      (__attribute__((address_space(3))) void*)(l), 16, 0, 0)

// ---- workspace layout (BYTE offsets; bf16 = 2 B/elem) ----
static const size_t OFF_XB  = 0;           // bf16 x      (16384,512)   16 MB
static const size_t OFF_QB  = 16777216;    // bf16 q*qscl (B,H,N,64)    16 MB
static const size_t OFF_KB  = 33554432;    // bf16 k                    16 MB
static const size_t OFF_VT  = 67108864;    // bf16 v^T    (B,H,64,N)    16 MB
static const size_t OFF_AO  = 83886080;    // bf16 attn out (16384,512) 16 MB
static const size_t OFF_WT  = 100663296;   // bf16 qkv_w^T (1536,512)  1.5 MB
static const size_t OFF_PWT = 102236160;   // bf16 proj_w^T (512,512)  0.5 MB
static const size_t OFF_XM  = 102760448;   // f32 xmean (B,N)
static const size_t OFF_XA  = 102825984;   // f32 xavg  (B,512)
static const size_t OFF_DF  = 102858752;   // f32 dfeat (B,N)
static const size_t OFF_CR  = 102924352;   // f32 crow2 (B,N)  [pre-scaled by aw*log2e]

// ---------- x row-mean + f32->bf16 convert ----------
__global__ __launch_bounds__(256) void k_xmean_cvt(const float* __restrict__ x,
                                                   float* __restrict__ xmean,
                                                   unsigned short* __restrict__ xb) {
  int row  = blockIdx.x * 4 + (threadIdx.x >> 6);
  int lane = threadIdx.x & 63;
  const float* px = x + (size_t)row * 512 + lane * 8;
  float4 a = ((const float4*)px)[0];
  float4 b = ((const float4*)px)[1];
  ushort8 o;
  o[0] = f2bf(a.x); o[1] = f2bf(a.y); o[2] = f2bf(a.z); o[3] = f2bf(a.w);
  o[4] = f2bf(b.x); o[5] = f2bf(b.y); o[6] = f2bf(b.z); o[7] = f2bf(b.w);
  *(ushort8*)(xb + (size_t)row * 512 + lane * 8) = o;
  float s = a.x + a.y + a.z + a.w + b.x + b.y + b.z + b.w;
  for (int off = 32; off; off >>= 1) s += __shfl_down(s, off);
  if (lane == 0) xmean[row] = s * (1.f / 512.f);
}

// ---------- x column sums over N from bf16 xb (partial, atomic) ----------
__global__ __launch_bounds__(512) void k_xavg(const unsigned short* __restrict__ xb,
                                              float* __restrict__ xavg) {
  int b = blockIdx.x, chunk = blockIdx.y;
  int c = threadIdx.x;
  const unsigned short* px = xb + ((size_t)b * 1024 + (size_t)chunk * 64) * 512 + c;
  float s = 0.f;
#pragma unroll 8
  for (int n = 0; n < 64; ++n) {
    unsigned u = (unsigned)px[(size_t)n * 512] << 16;
    s += *reinterpret_cast<float*>(&u);
  }
  atomicAdd(&xavg[b * 512 + c], s);
}

// ---------- fused DCT feature + head MLP -> crow (one block per batch) -------
__global__ __launch_bounds__(1024) void k_dct_headw(const float* __restrict__ xmean,
                                                    const float* __restrict__ xavg,
                                                    const float* __restrict__ h1w,
                                                    const float* __restrict__ h1b,
                                                    const float* __restrict__ h2w,
                                                    const float* __restrict__ h2b,
                                                    const float* __restrict__ freqw,
                                                    float* __restrict__ dfeat,
                                                    float* __restrict__ crow) {
  __shared__ float A[32][33], Dm[32][33], Tm[32][33];
  __shared__ float red[1024];
  __shared__ float nrm, tsum_s;
  __shared__ float xa[512];
  __shared__ float part[8][128];
  __shared__ float h1s[128];
  __shared__ float hw[8];
  int b = blockIdx.x, t = threadIdx.x;
  if (t < 512) xa[t] = xavg[b * 512 + t] * (1.f / 1024.f);
  int kk = t >> 5, nn = t & 31;
  A[kk][nn] = xmean[b * 1024 + t];
  float dv = (kk == 0) ? sqrtf(1.f / 32.f)
                       : sqrtf(2.f / 32.f) * cosf(PI_F * (2.f * nn + 1.f) * (float)kk / 64.f);
  Dm[kk][nn] = dv;
  __syncthreads();
  float acc = 0.f;
  for (int m = 0; m < 32; ++m) acc += Dm[kk][m] * A[m][nn];
  Tm[kk][nn] = acc;
  __syncthreads();
  float acc2 = 0.f;
  for (int n = 0; n < 32; ++n) acc2 += Tm[kk][n] * Dm[nn][n];
  float val = fminf(fmaxf(acc2, -10.f), 10.f);
  red[t] = val * val;
  __syncthreads();
  for (int s = 512; s; s >>= 1) { if (t < s) red[t] += red[t + s]; __syncthreads(); }
  if (t == 0) nrm = sqrtf(red[0]) + 1e-5f;
  __syncthreads();
  float dn = val / nrm;
  dfeat[b * 1024 + t] = dn;
  red[t] = dn;
  __syncthreads();
  for (int s = 512; s; s >>= 1) { if (t < s) red[t] += red[t + s]; __syncthreads(); }
  if (t == 0) tsum_s = red[0];
  {
    int j = t & 127, c = t >> 7;
    float a1 = 0.f;
    const float* wcol = h1w + (size_t)c * 64 * 128 + j;
#pragma unroll 8
    for (int i = 0; i < 64; ++i) a1 += xa[c * 64 + i] * wcol[(size_t)i * 128];
    part[c][j] = a1;
  }
  __syncthreads();
  if (t < 128) {
    float a1 = h1b[t];
#pragma unroll
    for (int c = 0; c < 8; ++c) a1 += part[c][t];
    h1s[t] = fmaxf(a1, 0.f);
  }
  __syncthreads();
  if (t < 8) {
    float a2 = h2b[t];
    for (int j = 0; j < 128; ++j) a2 += h1s[j] * h2w[j * 8 + t];
    hw[t] = a2;
  }
  __syncthreads();
  float s2 = 0.f;
#pragma unroll
  for (int h = 0; h < 8; ++h) s2 += hw[h] * hw[h];
  float Tb = tsum_s;
  const float aw2 = (1.f / (1.f + __expf(-freqw[0]))) * LOG2E;
  float p = s2 * dn;
  crow[b * 1024 + t] = aw2 * p / fmaxf(p * Tb, 1e-5f);
}

// ---------- merged weight transpose+convert (qkv_w and proj_w in one grid) ----
__global__ __launch_bounds__(256) void k_wtrans2(const float* __restrict__ w1,
                                                 unsigned short* __restrict__ wt1,
                                                 const float* __restrict__ w2,
                                                 unsigned short* __restrict__ wt2) {
  __shared__ unsigned short T[64 * 65];
  int bx = blockIdx.x;
  const float* w;
  unsigned short* wt;
  int Nw, n0;
  if (bx < 24) { w = w1; wt = wt1; Nw = 1536; n0 = bx * 64; }
  else         { w = w2; wt = wt2; Nw = 512;  n0 = (bx - 24) * 64; }
  int k0 = blockIdx.y * 64;
  int t = threadIdx.x;
  int r = t >> 2, c0 = (t & 3) * 16;
  const float* src = w + (size_t)(k0 + r) * Nw + n0 + c0;
#pragma unroll
  for (int q = 0; q < 4; ++q) {
    float4 v4 = *(const float4*)(src + q * 4);
    T[(c0 + q * 4 + 0) * 65 + r] = f2bf(v4.x);
    T[(c0 + q * 4 + 1) * 65 + r] = f2bf(v4.y);
    T[(c0 + q * 4 + 2) * 65 + r] = f2bf(v4.z);
    T[(c0 + q * 4 + 3) * 65 + r] = f2bf(v4.w);
  }
  __syncthreads();
  int nl = t >> 2, koff = (t & 3) * 16;
  ushort8 o0, o1;
#pragma unroll
  for (int e = 0; e < 8; ++e) o0[e] = T[nl * 65 + koff + e];
#pragma unroll
  for (int e = 0; e < 8; ++e) o1[e] = T[nl * 65 + koff + 8 + e];
  unsigned short* dst = wt + (size_t)(n0 + nl) * 512 + k0 + koff;
  *(ushort8*)(dst) = o0;
  *(ushort8*)(dst + 8) = o1;
}

// ---------- bf16 MFMA GEMM, 128x128, BK=64, gload_lds + XOR preswizzle --------
template <int MODE>
__global__ __launch_bounds__(256) void k_gemm(const unsigned short* __restrict__ A,
                                              const unsigned short* __restrict__ Bt,
                                              const float* __restrict__ bias,
                                              const float* __restrict__ freqw,
                                              unsigned short* __restrict__ o_q,
                                              unsigned short* __restrict__ o_k,
                                              unsigned short* __restrict__ o_vt,
                                              float* __restrict__ o_f) {
  __shared__ __align__(16) unsigned short As[128 * 64];
  __shared__ __align__(16) unsigned short Bs[128 * 64];
  const int t = threadIdx.x, w = t >> 6, l = t & 63;
  const int lg = l >> 4, ln = l & 15;
  const int wm = w >> 1, wn = w & 1;
  constexpr int NX = (MODE == 0) ? 12 : 4;
  const int bid = blockIdx.x, xcd = bid & 7, idx = bid >> 3;
  const int bx = idx % NX, by = xcd * 16 + idx / NX;
  const int row0 = by * 128, col0 = bx * 128;

  f32x4 acc[4][4];
#pragma unroll
  for (int i = 0; i < 4; ++i)
#pragma unroll
    for (int j = 0; j < 4; ++j) acc[i][j] = (f32x4){0.f, 0.f, 0.f, 0.f};

  int aoff[4][2], boff[4][2];
#pragma unroll
  for (int mt = 0; mt < 4; ++mt)
#pragma unroll
    for (int ks = 0; ks < 2; ++ks) {
      int ra = wm * 64 + mt * 16 + ln;
      aoff[mt][ks] = ra * 64 + (((lg + ks * 4) ^ (ra & 7)) << 3);
      int rb = wn * 64 + mt * 16 + ln;
      boff[mt][ks] = rb * 64 + (((lg + ks * 4) ^ (rb & 7)) << 3);
    }

  for (int k0 = 0; k0 < 512; k0 += 64) {
#pragma unroll
    for (int j = 0; j < 4; ++j) {
      int g = (j * 4 + w) * 64 + l;
      int row = g >> 3, slot = g & 7;
      int ss = slot ^ (row & 7);
      GLOAD16(A + (size_t)(row0 + row) * 512 + k0 + ss * 8, As + (size_t)(j * 4 + w) * 512);
      GLOAD16(Bt + (size_t)(col0 + row) * 512 + k0 + ss * 8, Bs + (size_t)(j * 4 + w) * 512);
    }
    __syncthreads();
#pragma unroll
    for (int ks = 0; ks < 2; ++ks) {
      bf16x8 av[4], bv[4];
#pragma unroll
      for (int mt = 0; mt < 4; ++mt) av[mt] = *(const bf16x8*)(As + aoff[mt][ks]);
#pragma unroll
      for (int nt = 0; nt < 4; ++nt) bv[nt] = *(const bf16x8*)(Bs + boff[nt][ks]);
#pragma unroll
      for (int mt = 0; mt < 4; ++mt)
#pragma unroll
        for (int nt = 0; nt < 4; ++nt)
          acc[mt][nt] = __builtin_amdgcn_mfma_f32_16x16x32_bf16(av[mt], bv[nt], acc[mt][nt], 0, 0, 0);
    }
    __syncthreads();
  }

  if (MODE == 0) {
    const int sel = col0 >> 9;
    if (sel == 2) {
      unsigned short* T = (wn == 0) ? As : Bs;
#pragma unroll
      for (int nt = 0; nt < 4; ++nt) {
        int dcol = nt * 16 + ln;
        float bcol = bias[col0 + wn * 64 + dcol];
#pragma unroll
        for (int mt = 0; mt < 4; ++mt)
#pragma unroll
          for (int r = 0; r < 4; ++r) {
            int rowL = wm * 64 + mt * 16 + lg * 4 + r;
            int slot = (rowL >> 3) ^ (dcol & 7);
            T[dcol * 128 + slot * 8 + (rowL & 7)] = f2bf(acc[mt][nt][r] + bcol);
          }
      }
      __syncthreads();
      int b_ = row0 >> 10, n0 = row0 & 1023;
      int h0 = (col0 & 511) >> 6;
      int dcol = t >> 2, rseg = (t & 3) * 32;
#pragma unroll
      for (int half = 0; half < 2; ++half) {
        const unsigned short* S = half ? Bs : As;
        size_t plane = ((size_t)(b_ * 8 + h0 + half)) << 16;
        unsigned short* dst = o_vt + plane + (size_t)dcol * 1024 + n0 + rseg;
#pragma unroll
        for (int j = 0; j < 4; ++j) {
          int slot = ((rseg >> 3) + j) ^ (dcol & 7);
          *(ushort8*)(dst + j * 8) = *(const ushort8*)(S + dcol * 128 + slot * 8);
        }
      }
      return;
    }
    unsigned short* outp = (sel == 0) ? o_q : o_k;
    const float aw = 1.f / (1.f + __expf(-freqw[0]));
    const float scl = (sel == 0) ? 0.125f * (1.f - aw) * LOG2E : 1.f;
#pragma unroll
    for (int nt = 0; nt < 4; ++nt) {
      int colg = col0 + wn * 64 + nt * 16 + ln;
      float bcol = bias[colg];
      int h = (colg >> 6) & 7, d = colg & 63;
#pragma unroll
      for (int mt = 0; mt < 4; ++mt)
#pragma unroll
        for (int r = 0; r < 4; ++r) {
          int row = row0 + wm * 64 + mt * 16 + lg * 4 + r;
          int bidx = row >> 10, n = row & 1023;
          float val = (acc[mt][nt][r] + bcol) * scl;
          outp[(((size_t)(bidx * 8 + h)) << 16) + (n << 6) + d] = f2bf(val);
        }
    }
  } else {
#pragma unroll
    for (int nt = 0; nt < 4; ++nt) {
      int colg = col0 + wn * 64 + nt * 16 + ln;
      float bcol = bias[colg];
#pragma unroll
      for (int mt = 0; mt < 4; ++mt)
#pragma unroll
        for (int r = 0; r < 4; ++r) {
          int row = row0 + wm * 64 + mt * 16 + lg * 4 + r;
          o_f[(size_t)row * 512 + colg] = acc[mt][nt][r] + bcol;
        }
    }
  }
}

// ---------- flash attention: QK-hoist pipeline (QK(kt+1) || softmax(kt)) -----
// dbuf K/V, counted vmcnt(2), two named S-buffers (manual unroll-by-2).
__global__ __launch_bounds__(256) void k_attn(const unsigned short* __restrict__ qb,
                                              const unsigned short* __restrict__ kb,
                                              const unsigned short* __restrict__ vtg,
                                              const float* __restrict__ crow,
                                              const float* __restrict__ dfeat,
                                              const float* __restrict__ freqw,
                                              unsigned short* __restrict__ ao) {
  __shared__ __align__(16) unsigned short Ks[2][64 * 64];
  __shared__ __align__(16) unsigned short Vs[2][64 * 64];
  __shared__ __align__(16) unsigned short Ps[4][32 * 64];
  __shared__ __align__(16) float Df[1024];
  const int bid = blockIdx.x, xcd = bid & 7, idx = bid >> 3;
  const int bh = xcd * 16 + (idx >> 3), qt = idx & 7;
  const int b = bh >> 3, h = bh & 7;
  const int t = threadIdx.x, w = t >> 6, l = t & 63;
  const int lg = l >> 4, ln = l & 15;
  const size_t base = ((size_t)(b * 8 + h)) << 16;
  const float aw2 = (1.f / (1.f + __expf(-freqw[0]))) * LOG2E;

  *(float4*)(&Df[t * 4]) = *(const float4*)(dfeat + b * 1024 + t * 4);

  const int qrow0 = qt * 128 + w * 32;
  bf16x8 qf[2][2];
#pragma unroll
  for (int mt = 0; mt < 2; ++mt)
#pragma unroll
    for (int ks = 0; ks < 2; ++ks)
      qf[mt][ks] = *(const bf16x8*)(qb + base + (size_t)(qrow0 + mt * 16 + ln) * 64 + lg * 8 + ks * 32);

  float cr2[2][4];
#pragma unroll
  for (int mt = 0; mt < 2; ++mt)
#pragma unroll
    for (int r = 0; r < 4; ++r)
      cr2[mt][r] = crow[b * 1024 + qrow0 + mt * 16 + lg * 4 + r];

  f32x4 accO[2][4];
#pragma unroll
  for (int mt = 0; mt < 2; ++mt)
#pragma unroll
    for (int dt = 0; dt < 4; ++dt) accO[mt][dt] = (f32x4){0.f, 0.f, 0.f, 0.f};
  float mrow[2][4], psum[2][4];
#pragma unroll
  for (int mt = 0; mt < 2; ++mt)
#pragma unroll
    for (int r = 0; r < 4; ++r) { mrow[mt][r] = -1e30f; psum[mt][r] = 0.f; }

  int rdoff[2];
#pragma unroll
  for (int ks = 0; ks < 2; ++ks) rdoff[ks] = ln * 64 + (((lg + ks * 4) ^ (ln & 7)) << 3);
  int pwoff[4][4];
#pragma unroll
  for (int nt = 0; nt < 4; ++nt)
#pragma unroll
    for (int r = 0; r < 4; ++r) {
      int prow = lg * 4 + r;
      pwoff[nt][r] = prow * 64 + ((((nt << 1) | (ln >> 3)) ^ (prow & 7)) << 3) + (ln & 7);
    }

  const int g0 = w * 64 + l, g1 = (4 + w) * 64 + l;
  const int srow0 = g0 >> 3, sslot0 = (g0 & 7) ^ (srow0 & 7);
  const int srow1 = g1 >> 3, sslot1 = (g1 & 7) ^ (srow1 & 7);

  // prologue: stage tiles 0 and 1; full drain (compiler loads also in flight)
  GLOAD16(kb + base + (size_t)srow0 * 64 + sslot0 * 8, Ks[0] + (size_t)w * 512);
  GLOAD16(kb + base + (size_t)srow1 * 64 + sslot1 * 8, Ks[0] + (size_t)(4 + w) * 512);
  GLOAD16(vtg + base + (size_t)srow0 * 1024 + sslot0 * 8, Vs[0] + (size_t)w * 512);
  GLOAD16(vtg + base + (size_t)srow1 * 1024 + sslot1 * 8, Vs[0] + (size_t)(4 + w) * 512);
  GLOAD16(kb + base + (size_t)(64 + srow0) * 64 + sslot0 * 8, Ks[1] + (size_t)w * 512);
  GLOAD16(kb + base + (size_t)(64 + srow1) * 64 + sslot1 * 8, Ks[1] + (size_t)(4 + w) * 512);
  GLOAD16(vtg + base + (size_t)srow0 * 1024 + 64 + sslot0 * 8, Vs[1] + (size_t)w * 512);
  GLOAD16(vtg + base + (size_t)srow1 * 1024 + 64 + sslot1 * 8, Vs[1] + (size_t)(4 + w) * 512);
  asm volatile("s_waitcnt vmcnt(0) lgkmcnt(0)" ::: "memory");
  __builtin_amdgcn_s_barrier();

  f32x4 sA[2][4], sB[2][4];

  // QK(0) -> sA (bias C-init from Df)
  {
    float dmv[4];
#pragma unroll
    for (int nt = 0; nt < 4; ++nt) dmv[nt] = Df[nt * 16 + ln];
#pragma unroll
    for (int mt = 0; mt < 2; ++mt)
#pragma unroll
      for (int nt = 0; nt < 4; ++nt)
#pragma unroll
        for (int r = 0; r < 4; ++r)
          sA[mt][nt][r] = __builtin_amdgcn_fmed3f(cr2[mt][r] * dmv[nt], 0.f, aw2);
#pragma unroll
    for (int nt = 0; nt < 4; ++nt) {
      bf16x8 kf0 = *(const bf16x8*)(Ks[0] + nt * 1024 + rdoff[0]);
      bf16x8 kf1 = *(const bf16x8*)(Ks[0] + nt * 1024 + rdoff[1]);
#pragma unroll
      for (int mt = 0; mt < 2; ++mt) {
        sA[mt][nt] = __builtin_amdgcn_mfma_f32_16x16x32_bf16(qf[mt][0], kf0, sA[mt][nt], 0, 0, 0);
        sA[mt][nt] = __builtin_amdgcn_mfma_f32_16x16x32_bf16(qf[mt][1], kf1, sA[mt][nt], 0, 0, 0);
      }
    }
  }

  auto body = [&](f32x4 (&sC)[2][4], f32x4 (&sN)[2][4], const int kt) {
    const int cur = kt & 1;
    if (kt == 15) { asm volatile("s_waitcnt vmcnt(0)" ::: "memory"); }
    else          { asm volatile("s_waitcnt vmcnt(2)" ::: "memory"); }
    __builtin_amdgcn_s_barrier();  // tile kt's V and tile kt+1's K visible

    // QK(kt+1) -> sN (issues MFMAs; latency hides under softmax below)
    if (kt < 15) {
      float dmv[4];
#pragma unroll
      for (int nt = 0; nt < 4; ++nt) dmv[nt] = Df[(kt + 1) * 64 + nt * 16 + ln];
#pragma unroll
      for (int mt = 0; mt < 2; ++mt)
#pragma unroll
        for (int nt = 0; nt < 4; ++nt)
#pragma unroll
          for (int r = 0; r < 4; ++r)
            sN[mt][nt][r] = __builtin_amdgcn_fmed3f(cr2[mt][r] * dmv[nt], 0.f, aw2);
      __builtin_amdgcn_s_setprio(1);
#pragma unroll
      for (int nt = 0; nt < 4; ++nt) {
        bf16x8 kf0 = *(const bf16x8*)(Ks[cur ^ 1] + nt * 1024 + rdoff[0]);
        bf16x8 kf1 = *(const bf16x8*)(Ks[cur ^ 1] + nt * 1024 + rdoff[1]);
#pragma unroll
        for (int mt = 0; mt < 2; ++mt) {
          sN[mt][nt] = __builtin_amdgcn_mfma_f32_16x16x32_bf16(qf[mt][0], kf0, sN[mt][nt], 0, 0, 0);
          sN[mt][nt] = __builtin_amdgcn_mfma_f32_16x16x32_bf16(qf[mt][1], kf1, sN[mt][nt], 0, 0, 0);
        }
      }
      __builtin_amdgcn_s_setprio(0);
    }
    // prefetch K(kt+2) into Ks[cur] (last read: QK(kt), a barrier ago)
    if (kt < 14) {
      GLOAD16(kb + base + (size_t)((kt + 2) * 64 + srow0) * 64 + sslot0 * 8, Ks[cur] + (size_t)w * 512);
      GLOAD16(kb + base + (size_t)((kt + 2) * 64 + srow1) * 64 + sslot1 * 8, Ks[cur] + (size_t)(4 + w) * 512);
    }

    // softmax on sC (tile kt) — overlaps QK(kt+1) MFMA latency
    float lmax[2][4];
    bool viol = false;
#pragma unroll
    for (int mt = 0; mt < 2; ++mt)
#pragma unroll
      for (int r = 0; r < 4; ++r) {
        lmax[mt][r] = fmaxf(fmaxf(sC[mt][0][r], sC[mt][1][r]), fmaxf(sC[mt][2][r], sC[mt][3][r]));
        viol = viol || (lmax[mt][r] > mrow[mt][r] + 8.f);
      }
    if (__any(viol)) {
#pragma unroll
      for (int mt = 0; mt < 2; ++mt)
#pragma unroll
        for (int r = 0; r < 4; ++r) {
          float pmax = lmax[mt][r];
          pmax = fmaxf(pmax, __shfl_xor(pmax, 1));
          pmax = fmaxf(pmax, __shfl_xor(pmax, 2));
          pmax = fmaxf(pmax, __shfl_xor(pmax, 4));
          pmax = fmaxf(pmax, __shfl_xor(pmax, 8));
          float mnew = fmaxf(mrow[mt][r], pmax);
          float sc = __builtin_amdgcn_exp2f(mrow[mt][r] - mnew);
          psum[mt][r] *= sc;
          mrow[mt][r] = mnew;
#pragma unroll
          for (int dt = 0; dt < 4; ++dt) accO[mt][dt][r] *= sc;
        }
    }
#pragma unroll
    for (int mt = 0; mt < 2; ++mt)
#pragma unroll
      for (int r = 0; r < 4; ++r) {
        float p0 = __builtin_amdgcn_exp2f(sC[mt][0][r] - mrow[mt][r]);
        float p1 = __builtin_amdgcn_exp2f(sC[mt][1][r] - mrow[mt][r]);
        float p2 = __builtin_amdgcn_exp2f(sC[mt][2][r] - mrow[mt][r]);
        float p3 = __builtin_amdgcn_exp2f(sC[mt][3][r] - mrow[mt][r]);
        psum[mt][r] += (p0 + p1) + (p2 + p3);
        Ps[w][mt * 1024 + pwoff[0][r]] = f2bf_hw(p0);
        Ps[w][mt * 1024 + pwoff[1][r]] = f2bf_hw(p1);
        Ps[w][mt * 1024 + pwoff[2][r]] = f2bf_hw(p2);
        Ps[w][mt * 1024 + pwoff[3][r]] = f2bf_hw(p3);
      }

    // PV(kt)
    bf16x8 pa[2][2];
#pragma unroll
    for (int mt = 0; mt < 2; ++mt)
#pragma unroll
      for (int ks = 0; ks < 2; ++ks)
        pa[mt][ks] = *(const bf16x8*)(Ps[w] + mt * 1024 + rdoff[ks]);
    __builtin_amdgcn_s_setprio(1);
#pragma unroll
    for (int dt = 0; dt < 4; ++dt) {
      bf16x8 vf0 = *(const bf16x8*)(Vs[cur] + dt * 1024 + rdoff[0]);
      bf16x8 vf1 = *(const bf16x8*)(Vs[cur] + dt * 1024 + rdoff[1]);
#pragma unroll
      for (int mt = 0; mt < 2; ++mt) {
        accO[mt][dt] = __builtin_amdgcn_mfma_f32_16x16x32_bf16(pa[mt][0], vf0, accO[mt][dt], 0, 0, 0);
        accO[mt][dt] = __builtin_amdgcn_mfma_f32_16x16x32_bf16(pa[mt][1], vf1, accO[mt][dt], 0, 0, 0);
      }
    }
    __builtin_amdgcn_s_setprio(0);

    asm volatile("s_waitcnt lgkmcnt(0)" ::: "memory");
    __builtin_amdgcn_s_barrier();  // all waves done reading Vs[cur] / own ds ops
    // prefetch V(kt+2) into Vs[cur]
    if (kt < 14) {
      GLOAD16(vtg + base + (size_t)srow0 * 1024 + (kt + 2) * 64 + sslot0 * 8, Vs[cur] + (size_t)w * 512);
      GLOAD16(vtg + base + (size_t)srow1 * 1024 + (kt + 2) * 64 + sslot1 * 8, Vs[cur] + (size_t)(4 + w) * 512);
    }
  };

  for (int kt = 0; kt < 16; kt += 2) {
    body(sA, sB, kt);
    body(sB, sA, kt + 1);
  }

#pragma unroll
  for (int mt = 0; mt < 2; ++mt)
#pragma unroll
    for (int r = 0; r < 4; ++r) {
      float lr = psum[mt][r];
      lr += __shfl_xor(lr, 1);
      lr += __shfl_xor(lr, 2);
      lr += __shfl_xor(lr, 4);
      lr += __shfl_xor(lr, 8);
      float inv = 1.f / lr;
      int n = qrow0 + mt * 16 + lg * 4 + r;
#pragma unroll
      for (int dt = 0; dt < 4; ++dt)
        ao[((size_t)(b * 1024 + n)) * 512 + h * 64 + dt * 16 + ln] = f2bf(accO[mt][dt][r] * inv);
    }
}

extern "C" void kernel_launch(void* const* d_in, const int* in_sizes, int n_in,
                              void* d_out, int out_size, void* d_ws, size_t ws_size,
                              hipStream_t stream) {
  const float* x      = (const float*)d_in[0];
  const float* qkv_w  = (const float*)d_in[1];
  const float* qkv_b  = (const float*)d_in[2];
  const float* proj_w = (const float*)d_in[3];
  const float* proj_b = (const float*)d_in[4];
  const float* h1_w   = (const float*)d_in[5];
  const float* h1_b   = (const float*)d_in[6];
  const float* h2_w   = (const float*)d_in[7];
  const float* h2_b   = (const float*)d_in[8];
  const float* freq_w = (const float*)d_in[9];

  char* ws = (char*)d_ws;
  unsigned short* xb  = (unsigned short*)(ws + OFF_XB);
  unsigned short* qbp = (unsigned short*)(ws + OFF_QB);
  unsigned short* kbp = (unsigned short*)(ws + OFF_KB);
  unsigned short* vtg = (unsigned short*)(ws + OFF_VT);
  unsigned short* ao  = (unsigned short*)(ws + OFF_AO);
  unsigned short* wt  = (unsigned short*)(ws + OFF_WT);
  unsigned short* pwt = (unsigned short*)(ws + OFF_PWT);
  float* xmean = (float*)(ws + OFF_XM);
  float* xavg  = (float*)(ws + OFF_XA);
  float* dfeat = (float*)(ws + OFF_DF);
  float* crow  = (float*)(ws + OFF_CR);
  float* out   = (float*)d_out;

  hipMemsetAsync(xavg, 0, 16 * 512 * sizeof(float), stream);

  k_xmean_cvt<<<dim3(4096), 256, 0, stream>>>(x, xmean, xb);
  k_xavg<<<dim3(16, 16), 512, 0, stream>>>(xb, xavg);
  k_wtrans2<<<dim3(32, 8), 256, 0, stream>>>(qkv_w, wt, proj_w, pwt);
  k_dct_headw<<<dim3(16), 1024, 0, stream>>>(xmean, xavg, h1_w, h1_b, h2_w, h2_b,
                                             freq_w, dfeat, crow);
  k_gemm<0><<<dim3(12 * 128), 256, 0, stream>>>(xb, wt, qkv_b, freq_w, qbp, kbp, vtg, nullptr);
  k_attn<<<dim3(1024), 256, 0, stream>>>(qbp, kbp, vtg, crow, dfeat, freq_w, ao);
  k_gemm<1><<<dim3(4 * 128), 256, 0, stream>>>(ao, pwt, proj_b, freq_w, nullptr, nullptr, nullptr, out);
}

// Round 18
// 167.762 us; speedup vs baseline: 1.2171x; 1.2171x over previous
//
#include <hip/hip_runtime.h>
#include <hip/hip_bf16.h>
#include <math.h>

#define PI_F  3.14159265358979323846f
#define LOG2E 1.44269504088896340736f

typedef __attribute__((ext_vector_type(8))) short          bf16x8;
typedef __attribute__((ext_vector_type(8))) unsigned short ushort8;
typedef __attribute__((ext_vector_type(4))) float          f32x4;

__device__ __forceinline__ unsigned short f2bf(float f) {
  union { float f; unsigned u; } v; v.f = f;
  unsigned r = v.u + 0x7fffu + ((v.u >> 16) & 1u);
  return (unsigned short)(r >> 16);
}

__device__ __forceinline__ unsigned short f2bf_hw(float f) {
  __hip_bfloat16 h = __float2bfloat16(f);
  return *reinterpret_cast<unsigned short*>(&h);
}

#define GLOAD16(g, l)                                                         \
  __builtin_amdgcn_global_load_lds(                                           \
      (const __attribute__((address_space(1))) void*)(g),                     \
      (__attribute__((address_space(3))) void*)(l), 16, 0, 0)

// ---- workspace layout (BYTE offsets; bf16 = 2 B/elem) ----
static const size_t OFF_XB  = 0;           // bf16 x      (16384,512)   16 MB
static const size_t OFF_QB  = 16777216;    // bf16 q*qscl (B,H,N,64)    16 MB
static const size_t OFF_KB  = 33554432;    // bf16 k                    16 MB
static const size_t OFF_VT  = 67108864;    // bf16 v^T    (B,H,64,N)    16 MB
static const size_t OFF_AO  = 83886080;    // bf16 attn out (16384,512) 16 MB
static const size_t OFF_WT  = 100663296;   // bf16 qkv_w^T (1536,512)  1.5 MB
static const size_t OFF_PWT = 102236160;   // bf16 proj_w^T (512,512)  0.5 MB
static const size_t OFF_XM  = 102760448;   // f32 xmean (B,N)
static const size_t OFF_XA  = 102825984;   // f32 xavg  (B,512)
static const size_t OFF_DF  = 102858752;   // f32 dfeat (B,N)
static const size_t OFF_CR  = 102924352;   // f32 crow2 (B,N)  [pre-scaled by aw*log2e]

// ---------- x row-mean + f32->bf16 convert ----------
__global__ __launch_bounds__(256) void k_xmean_cvt(const float* __restrict__ x,
                                                   float* __restrict__ xmean,
                                                   unsigned short* __restrict__ xb) {
  int row  = blockIdx.x * 4 + (threadIdx.x >> 6);
  int lane = threadIdx.x & 63;
  const float* px = x + (size_t)row * 512 + lane * 8;
  float4 a = ((const float4*)px)[0];
  float4 b = ((const float4*)px)[1];
  ushort8 o;
  o[0] = f2bf(a.x); o[1] = f2bf(a.y); o[2] = f2bf(a.z); o[3] = f2bf(a.w);
  o[4] = f2bf(b.x); o[5] = f2bf(b.y); o[6] = f2bf(b.z); o[7] = f2bf(b.w);
  *(ushort8*)(xb + (size_t)row * 512 + lane * 8) = o;
  float s = a.x + a.y + a.z + a.w + b.x + b.y + b.z + b.w;
  for (int off = 32; off; off >>= 1) s += __shfl_down(s, off);
  if (lane == 0) xmean[row] = s * (1.f / 512.f);
}

// ---------- x column sums over N from bf16 xb (partial, atomic) ----------
__global__ __launch_bounds__(512) void k_xavg(const unsigned short* __restrict__ xb,
                                              float* __restrict__ xavg) {
  int b = blockIdx.x, chunk = blockIdx.y;
  int c = threadIdx.x;
  const unsigned short* px = xb + ((size_t)b * 1024 + (size_t)chunk * 64) * 512 + c;
  float s = 0.f;
#pragma unroll 8
  for (int n = 0; n < 64; ++n) {
    unsigned u = (unsigned)px[(size_t)n * 512] << 16;
    s += *reinterpret_cast<float*>(&u);
  }
  atomicAdd(&xavg[b * 512 + c], s);
}

// ---------- fused DCT feature + head MLP -> crow (one block per batch) -------
__global__ __launch_bounds__(1024) void k_dct_headw(const float* __restrict__ xmean,
                                                    const float* __restrict__ xavg,
                                                    const float* __restrict__ h1w,
                                                    const float* __restrict__ h1b,
                                                    const float* __restrict__ h2w,
                                                    const float* __restrict__ h2b,
                                                    const float* __restrict__ freqw,
                                                    float* __restrict__ dfeat,
                                                    float* __restrict__ crow) {
  __shared__ float A[32][33], Dm[32][33], Tm[32][33];
  __shared__ float red[1024];
  __shared__ float nrm, tsum_s;
  __shared__ float xa[512];
  __shared__ float part[8][128];
  __shared__ float h1s[128];
  __shared__ float hw[8];
  int b = blockIdx.x, t = threadIdx.x;
  if (t < 512) xa[t] = xavg[b * 512 + t] * (1.f / 1024.f);
  int kk = t >> 5, nn = t & 31;
  A[kk][nn] = xmean[b * 1024 + t];
  float dv = (kk == 0) ? sqrtf(1.f / 32.f)
                       : sqrtf(2.f / 32.f) * cosf(PI_F * (2.f * nn + 1.f) * (float)kk / 64.f);
  Dm[kk][nn] = dv;
  __syncthreads();
  float acc = 0.f;
  for (int m = 0; m < 32; ++m) acc += Dm[kk][m] * A[m][nn];
  Tm[kk][nn] = acc;
  __syncthreads();
  float acc2 = 0.f;
  for (int n = 0; n < 32; ++n) acc2 += Tm[kk][n] * Dm[nn][n];
  float val = fminf(fmaxf(acc2, -10.f), 10.f);
  red[t] = val * val;
  __syncthreads();
  for (int s = 512; s; s >>= 1) { if (t < s) red[t] += red[t + s]; __syncthreads(); }
  if (t == 0) nrm = sqrtf(red[0]) + 1e-5f;
  __syncthreads();
  float dn = val / nrm;
  dfeat[b * 1024 + t] = dn;
  red[t] = dn;
  __syncthreads();
  for (int s = 512; s; s >>= 1) { if (t < s) red[t] += red[t + s]; __syncthreads(); }
  if (t == 0) tsum_s = red[0];
  {
    int j = t & 127, c = t >> 7;
    float a1 = 0.f;
    const float* wcol = h1w + (size_t)c * 64 * 128 + j;
#pragma unroll 8
    for (int i = 0; i < 64; ++i) a1 += xa[c * 64 + i] * wcol[(size_t)i * 128];
    part[c][j] = a1;
  }
  __syncthreads();
  if (t < 128) {
    float a1 = h1b[t];
#pragma unroll
    for (int c = 0; c < 8; ++c) a1 += part[c][t];
    h1s[t] = fmaxf(a1, 0.f);
  }
  __syncthreads();
  if (t < 8) {
    float a2 = h2b[t];
    for (int j = 0; j < 128; ++j) a2 += h1s[j] * h2w[j * 8 + t];
    hw[t] = a2;
  }
  __syncthreads();
  float s2 = 0.f;
#pragma unroll
  for (int h = 0; h < 8; ++h) s2 += hw[h] * hw[h];
  float Tb = tsum_s;
  const float aw2 = (1.f / (1.f + __expf(-freqw[0]))) * LOG2E;
  float p = s2 * dn;
  crow[b * 1024 + t] = aw2 * p / fmaxf(p * Tb, 1e-5f);
}

// ---------- merged weight transpose+convert (qkv_w and proj_w in one grid) ----
__global__ __launch_bounds__(256) void k_wtrans2(const float* __restrict__ w1,
                                                 unsigned short* __restrict__ wt1,
                                                 const float* __restrict__ w2,
                                                 unsigned short* __restrict__ wt2) {
  __shared__ unsigned short T[64 * 65];
  int bx = blockIdx.x;
  const float* w;
  unsigned short* wt;
  int Nw, n0;
  if (bx < 24) { w = w1; wt = wt1; Nw = 1536; n0 = bx * 64; }
  else         { w = w2; wt = wt2; Nw = 512;  n0 = (bx - 24) * 64; }
  int k0 = blockIdx.y * 64;
  int t = threadIdx.x;
  int r = t >> 2, c0 = (t & 3) * 16;
  const float* src = w + (size_t)(k0 + r) * Nw + n0 + c0;
#pragma unroll
  for (int q = 0; q < 4; ++q) {
    float4 v4 = *(const float4*)(src + q * 4);
    T[(c0 + q * 4 + 0) * 65 + r] = f2bf(v4.x);
    T[(c0 + q * 4 + 1) * 65 + r] = f2bf(v4.y);
    T[(c0 + q * 4 + 2) * 65 + r] = f2bf(v4.z);
    T[(c0 + q * 4 + 3) * 65 + r] = f2bf(v4.w);
  }
  __syncthreads();
  int nl = t >> 2, koff = (t & 3) * 16;
  ushort8 o0, o1;
#pragma unroll
  for (int e = 0; e < 8; ++e) o0[e] = T[nl * 65 + koff + e];
#pragma unroll
  for (int e = 0; e < 8; ++e) o1[e] = T[nl * 65 + koff + 8 + e];
  unsigned short* dst = wt + (size_t)(n0 + nl) * 512 + k0 + koff;
  *(ushort8*)(dst) = o0;
  *(ushort8*)(dst + 8) = o1;
}

// ---------- bf16 MFMA GEMM, 128x128, BK=64, gload_lds + XOR preswizzle --------
template <int MODE>
__global__ __launch_bounds__(256) void k_gemm(const unsigned short* __restrict__ A,
                                              const unsigned short* __restrict__ Bt,
                                              const float* __restrict__ bias,
                                              const float* __restrict__ freqw,
                                              unsigned short* __restrict__ o_q,
                                              unsigned short* __restrict__ o_k,
                                              unsigned short* __restrict__ o_vt,
                                              float* __restrict__ o_f) {
  __shared__ __align__(16) unsigned short As[128 * 64];
  __shared__ __align__(16) unsigned short Bs[128 * 64];
  const int t = threadIdx.x, w = t >> 6, l = t & 63;
  const int lg = l >> 4, ln = l & 15;
  const int wm = w >> 1, wn = w & 1;
  constexpr int NX = (MODE == 0) ? 12 : 4;
  const int bid = blockIdx.x, xcd = bid & 7, idx = bid >> 3;
  const int bx = idx % NX, by = xcd * 16 + idx / NX;
  const int row0 = by * 128, col0 = bx * 128;

  f32x4 acc[4][4];
#pragma unroll
  for (int i = 0; i < 4; ++i)
#pragma unroll
    for (int j = 0; j < 4; ++j) acc[i][j] = (f32x4){0.f, 0.f, 0.f, 0.f};

  int aoff[4][2], boff[4][2];
#pragma unroll
  for (int mt = 0; mt < 4; ++mt)
#pragma unroll
    for (int ks = 0; ks < 2; ++ks) {
      int ra = wm * 64 + mt * 16 + ln;
      aoff[mt][ks] = ra * 64 + (((lg + ks * 4) ^ (ra & 7)) << 3);
      int rb = wn * 64 + mt * 16 + ln;
      boff[mt][ks] = rb * 64 + (((lg + ks * 4) ^ (rb & 7)) << 3);
    }

  for (int k0 = 0; k0 < 512; k0 += 64) {
#pragma unroll
    for (int j = 0; j < 4; ++j) {
      int g = (j * 4 + w) * 64 + l;
      int row = g >> 3, slot = g & 7;
      int ss = slot ^ (row & 7);
      GLOAD16(A + (size_t)(row0 + row) * 512 + k0 + ss * 8, As + (size_t)(j * 4 + w) * 512);
      GLOAD16(Bt + (size_t)(col0 + row) * 512 + k0 + ss * 8, Bs + (size_t)(j * 4 + w) * 512);
    }
    __syncthreads();
#pragma unroll
    for (int ks = 0; ks < 2; ++ks) {
      bf16x8 av[4], bv[4];
#pragma unroll
      for (int mt = 0; mt < 4; ++mt) av[mt] = *(const bf16x8*)(As + aoff[mt][ks]);
#pragma unroll
      for (int nt = 0; nt < 4; ++nt) bv[nt] = *(const bf16x8*)(Bs + boff[nt][ks]);
#pragma unroll
      for (int mt = 0; mt < 4; ++mt)
#pragma unroll
        for (int nt = 0; nt < 4; ++nt)
          acc[mt][nt] = __builtin_amdgcn_mfma_f32_16x16x32_bf16(av[mt], bv[nt], acc[mt][nt], 0, 0, 0);
    }
    __syncthreads();
  }

  if (MODE == 0) {
    const int sel = col0 >> 9;
    if (sel == 2) {
      unsigned short* T = (wn == 0) ? As : Bs;
#pragma unroll
      for (int nt = 0; nt < 4; ++nt) {
        int dcol = nt * 16 + ln;
        float bcol = bias[col0 + wn * 64 + dcol];
#pragma unroll
        for (int mt = 0; mt < 4; ++mt)
#pragma unroll
          for (int r = 0; r < 4; ++r) {
            int rowL = wm * 64 + mt * 16 + lg * 4 + r;
            int slot = (rowL >> 3) ^ (dcol & 7);
            T[dcol * 128 + slot * 8 + (rowL & 7)] = f2bf(acc[mt][nt][r] + bcol);
          }
      }
      __syncthreads();
      int b_ = row0 >> 10, n0 = row0 & 1023;
      int h0 = (col0 & 511) >> 6;
      int dcol = t >> 2, rseg = (t & 3) * 32;
#pragma unroll
      for (int half = 0; half < 2; ++half) {
        const unsigned short* S = half ? Bs : As;
        size_t plane = ((size_t)(b_ * 8 + h0 + half)) << 16;
        unsigned short* dst = o_vt + plane + (size_t)dcol * 1024 + n0 + rseg;
#pragma unroll
        for (int j = 0; j < 4; ++j) {
          int slot = ((rseg >> 3) + j) ^ (dcol & 7);
          *(ushort8*)(dst + j * 8) = *(const ushort8*)(S + dcol * 128 + slot * 8);
        }
      }
      return;
    }
    unsigned short* outp = (sel == 0) ? o_q : o_k;
    const float aw = 1.f / (1.f + __expf(-freqw[0]));
    const float scl = (sel == 0) ? 0.125f * (1.f - aw) * LOG2E : 1.f;
#pragma unroll
    for (int nt = 0; nt < 4; ++nt) {
      int colg = col0 + wn * 64 + nt * 16 + ln;
      float bcol = bias[colg];
      int h = (colg >> 6) & 7, d = colg & 63;
#pragma unroll
      for (int mt = 0; mt < 4; ++mt)
#pragma unroll
        for (int r = 0; r < 4; ++r) {
          int row = row0 + wm * 64 + mt * 16 + lg * 4 + r;
          int bidx = row >> 10, n = row & 1023;
          float val = (acc[mt][nt][r] + bcol) * scl;
          outp[(((size_t)(bidx * 8 + h)) << 16) + (n << 6) + d] = f2bf(val);
        }
    }
  } else {
#pragma unroll
    for (int nt = 0; nt < 4; ++nt) {
      int colg = col0 + wn * 64 + nt * 16 + ln;
      float bcol = bias[colg];
#pragma unroll
      for (int mt = 0; mt < 4; ++mt)
#pragma unroll
        for (int r = 0; r < 4; ++r) {
          int row = row0 + wm * 64 + mt * 16 + lg * 4 + r;
          o_f[(size_t)row * 512 + colg] = acc[mt][nt][r] + bcol;
        }
    }
  }
}

// ---------- flash attention: T4 counted-vmcnt double-buffered K/V ------------
// One raw barrier pair per tile; prefetch loads in flight across it (vmcnt(4)).
__global__ __launch_bounds__(256) void k_attn(const unsigned short* __restrict__ qb,
                                              const unsigned short* __restrict__ kb,
                                              const unsigned short* __restrict__ vtg,
                                              const float* __restrict__ crow,
                                              const float* __restrict__ dfeat,
                                              const float* __restrict__ freqw,
                                              unsigned short* __restrict__ ao) {
  __shared__ __align__(16) unsigned short Ks[2][64 * 64];
  __shared__ __align__(16) unsigned short Vs[2][64 * 64];
  __shared__ __align__(16) unsigned short Ps[4][32 * 64];
  __shared__ __align__(16) float Df[1024];
  const int bid = blockIdx.x, xcd = bid & 7, idx = bid >> 3;
  const int bh = xcd * 16 + (idx >> 3), qt = idx & 7;
  const int b = bh >> 3, h = bh & 7;
  const int t = threadIdx.x, w = t >> 6, l = t & 63;
  const int lg = l >> 4, ln = l & 15;
  const size_t base = ((size_t)(b * 8 + h)) << 16;
  const float aw2 = (1.f / (1.f + __expf(-freqw[0]))) * LOG2E;

  *(float4*)(&Df[t * 4]) = *(const float4*)(dfeat + b * 1024 + t * 4);

  const int qrow0 = qt * 128 + w * 32;
  bf16x8 qf[2][2];
#pragma unroll
  for (int mt = 0; mt < 2; ++mt)
#pragma unroll
    for (int ks = 0; ks < 2; ++ks)
      qf[mt][ks] = *(const bf16x8*)(qb + base + (size_t)(qrow0 + mt * 16 + ln) * 64 + lg * 8 + ks * 32);

  float cr2[2][4];
#pragma unroll
  for (int mt = 0; mt < 2; ++mt)
#pragma unroll
    for (int r = 0; r < 4; ++r)
      cr2[mt][r] = crow[b * 1024 + qrow0 + mt * 16 + lg * 4 + r];

  f32x4 accO[2][4];
#pragma unroll
  for (int mt = 0; mt < 2; ++mt)
#pragma unroll
    for (int dt = 0; dt < 4; ++dt) accO[mt][dt] = (f32x4){0.f, 0.f, 0.f, 0.f};
  float mrow[2][4], psum[2][4];
#pragma unroll
  for (int mt = 0; mt < 2; ++mt)
#pragma unroll
    for (int r = 0; r < 4; ++r) { mrow[mt][r] = -1e30f; psum[mt][r] = 0.f; }

  int rdoff[2];
#pragma unroll
  for (int ks = 0; ks < 2; ++ks) rdoff[ks] = ln * 64 + (((lg + ks * 4) ^ (ln & 7)) << 3);
  int pwoff[4][4];
#pragma unroll
  for (int nt = 0; nt < 4; ++nt)
#pragma unroll
    for (int r = 0; r < 4; ++r) {
      int prow = lg * 4 + r;
      pwoff[nt][r] = prow * 64 + ((((nt << 1) | (ln >> 3)) ^ (prow & 7)) << 3) + (ln & 7);
    }

  const int g0 = w * 64 + l, g1 = (4 + w) * 64 + l;
  const int srow0 = g0 >> 3, sslot0 = (g0 & 7) ^ (srow0 & 7);
  const int srow1 = g1 >> 3, sslot1 = (g1 & 7) ^ (srow1 & 7);

  GLOAD16(kb + base + (size_t)srow0 * 64 + sslot0 * 8, Ks[0] + (size_t)w * 512);
  GLOAD16(vtg + base + (size_t)srow0 * 1024 + sslot0 * 8, Vs[0] + (size_t)w * 512);
  GLOAD16(kb + base + (size_t)srow1 * 64 + sslot1 * 8, Ks[0] + (size_t)(4 + w) * 512);
  GLOAD16(vtg + base + (size_t)srow1 * 1024 + sslot1 * 8, Vs[0] + (size_t)(4 + w) * 512);

  for (int kt = 0; kt < 16; ++kt) {
    const int cur = kt & 1;
    asm volatile("s_waitcnt lgkmcnt(0)" ::: "memory");
    __builtin_amdgcn_s_barrier();
    if (kt < 15) {
      const int kn = kt + 1;
      GLOAD16(kb + base + (size_t)(kn * 64 + srow0) * 64 + sslot0 * 8, Ks[cur ^ 1] + (size_t)w * 512);
      GLOAD16(vtg + base + (size_t)srow0 * 1024 + kn * 64 + sslot0 * 8, Vs[cur ^ 1] + (size_t)w * 512);
      GLOAD16(kb + base + (size_t)(kn * 64 + srow1) * 64 + sslot1 * 8, Ks[cur ^ 1] + (size_t)(4 + w) * 512);
      GLOAD16(vtg + base + (size_t)srow1 * 1024 + kn * 64 + sslot1 * 8, Vs[cur ^ 1] + (size_t)(4 + w) * 512);
      asm volatile("s_waitcnt vmcnt(4)" ::: "memory");
    } else {
      asm volatile("s_waitcnt vmcnt(0)" ::: "memory");
    }
    __builtin_amdgcn_s_barrier();

    float dmv[4];
#pragma unroll
    for (int nt = 0; nt < 4; ++nt) dmv[nt] = Df[kt * 64 + nt * 16 + ln];
    f32x4 s[2][4];
#pragma unroll
    for (int mt = 0; mt < 2; ++mt)
#pragma unroll
      for (int nt = 0; nt < 4; ++nt)
#pragma unroll
        for (int r = 0; r < 4; ++r)
          s[mt][nt][r] = __builtin_amdgcn_fmed3f(cr2[mt][r] * dmv[nt], 0.f, aw2);
    __builtin_amdgcn_s_setprio(1);
#pragma unroll
    for (int nt = 0; nt < 4; ++nt) {
      bf16x8 kf0 = *(const bf16x8*)(Ks[cur] + nt * 1024 + rdoff[0]);
      bf16x8 kf1 = *(const bf16x8*)(Ks[cur] + nt * 1024 + rdoff[1]);
#pragma unroll
      for (int mt = 0; mt < 2; ++mt) {
        s[mt][nt] = __builtin_amdgcn_mfma_f32_16x16x32_bf16(qf[mt][0], kf0, s[mt][nt], 0, 0, 0);
        s[mt][nt] = __builtin_amdgcn_mfma_f32_16x16x32_bf16(qf[mt][1], kf1, s[mt][nt], 0, 0, 0);
      }
    }
    __builtin_amdgcn_s_setprio(0);

    float lmax[2][4];
    bool viol = false;
#pragma unroll
    for (int mt = 0; mt < 2; ++mt)
#pragma unroll
      for (int r = 0; r < 4; ++r) {
        lmax[mt][r] = fmaxf(fmaxf(s[mt][0][r], s[mt][1][r]), fmaxf(s[mt][2][r], s[mt][3][r]));
        viol = viol || (lmax[mt][r] > mrow[mt][r] + 8.f);
      }
    if (__any(viol)) {
#pragma unroll
      for (int mt = 0; mt < 2; ++mt)
#pragma unroll
        for (int r = 0; r < 4; ++r) {
          float pmax = lmax[mt][r];
          pmax = fmaxf(pmax, __shfl_xor(pmax, 1));
          pmax = fmaxf(pmax, __shfl_xor(pmax, 2));
          pmax = fmaxf(pmax, __shfl_xor(pmax, 4));
          pmax = fmaxf(pmax, __shfl_xor(pmax, 8));
          float mnew = fmaxf(mrow[mt][r], pmax);
          float sc = __builtin_amdgcn_exp2f(mrow[mt][r] - mnew);
          psum[mt][r] *= sc;
          mrow[mt][r] = mnew;
#pragma unroll
          for (int dt = 0; dt < 4; ++dt) accO[mt][dt][r] *= sc;
        }
    }
#pragma unroll
    for (int mt = 0; mt < 2; ++mt)
#pragma unroll
      for (int r = 0; r < 4; ++r) {
        float p0 = __builtin_amdgcn_exp2f(s[mt][0][r] - mrow[mt][r]);
        float p1 = __builtin_amdgcn_exp2f(s[mt][1][r] - mrow[mt][r]);
        float p2 = __builtin_amdgcn_exp2f(s[mt][2][r] - mrow[mt][r]);
        float p3 = __builtin_amdgcn_exp2f(s[mt][3][r] - mrow[mt][r]);
        psum[mt][r] += (p0 + p1) + (p2 + p3);
        Ps[w][mt * 1024 + pwoff[0][r]] = f2bf_hw(p0);
        Ps[w][mt * 1024 + pwoff[1][r]] = f2bf_hw(p1);
        Ps[w][mt * 1024 + pwoff[2][r]] = f2bf_hw(p2);
        Ps[w][mt * 1024 + pwoff[3][r]] = f2bf_hw(p3);
      }

    bf16x8 pa[2][2];
#pragma unroll
    for (int mt = 0; mt < 2; ++mt)
#pragma unroll
      for (int ks = 0; ks < 2; ++ks)
        pa[mt][ks] = *(const bf16x8*)(Ps[w] + mt * 1024 + rdoff[ks]);
    __builtin_amdgcn_s_setprio(1);
#pragma unroll
    for (int dt = 0; dt < 4; ++dt) {
      bf16x8 vf0 = *(const bf16x8*)(Vs[cur] + dt * 1024 + rdoff[0]);
      bf16x8 vf1 = *(const bf16x8*)(Vs[cur] + dt * 1024 + rdoff[1]);
#pragma unroll
      for (int mt = 0; mt < 2; ++mt) {
        accO[mt][dt] = __builtin_amdgcn_mfma_f32_16x16x32_bf16(pa[mt][0], vf0, accO[mt][dt], 0, 0, 0);
        accO[mt][dt] = __builtin_amdgcn_mfma_f32_16x16x32_bf16(pa[mt][1], vf1, accO[mt][dt], 0, 0, 0);
      }
    }
    __builtin_amdgcn_s_setprio(0);
  }

#pragma unroll
  for (int mt = 0; mt < 2; ++mt)
#pragma unroll
    for (int r = 0; r < 4; ++r) {
      float lr = psum[mt][r];
      lr += __shfl_xor(lr, 1);
      lr += __shfl_xor(lr, 2);
      lr += __shfl_xor(lr, 4);
      lr += __shfl_xor(lr, 8);
      float inv = 1.f / lr;
      int n = qrow0 + mt * 16 + lg * 4 + r;
#pragma unroll
      for (int dt = 0; dt < 4; ++dt)
        ao[((size_t)(b * 1024 + n)) * 512 + h * 64 + dt * 16 + ln] = f2bf(accO[mt][dt][r] * inv);
    }
}

extern "C" void kernel_launch(void* const* d_in, const int* in_sizes, int n_in,
                              void* d_out, int out_size, void* d_ws, size_t ws_size,
                              hipStream_t stream) {
  const float* x      = (const float*)d_in[0];
  const float* qkv_w  = (const float*)d_in[1];
  const float* qkv_b  = (const float*)d_in[2];
  const float* proj_w = (const float*)d_in[3];
  const float* proj_b = (const float*)d_in[4];
  const float* h1_w   = (const float*)d_in[5];
  const float* h1_b   = (const float*)d_in[6];
  const float* h2_w   = (const float*)d_in[7];
  const float* h2_b   = (const float*)d_in[8];
  const float* freq_w = (const float*)d_in[9];

  char* ws = (char*)d_ws;
  unsigned short* xb  = (unsigned short*)(ws + OFF_XB);
  unsigned short* qbp = (unsigned short*)(ws + OFF_QB);
  unsigned short* kbp = (unsigned short*)(ws + OFF_KB);
  unsigned short* vtg = (unsigned short*)(ws + OFF_VT);
  unsigned short* ao  = (unsigned short*)(ws + OFF_AO);
  unsigned short* wt  = (unsigned short*)(ws + OFF_WT);
  unsigned short* pwt = (unsigned short*)(ws + OFF_PWT);
  float* xmean = (float*)(ws + OFF_XM);
  float* xavg  = (float*)(ws + OFF_XA);
  float* dfeat = (float*)(ws + OFF_DF);
  float* crow  = (float*)(ws + OFF_CR);
  float* out   = (float*)d_out;

  hipMemsetAsync(xavg, 0, 16 * 512 * sizeof(float), stream);

  k_xmean_cvt<<<dim3(4096), 256, 0, stream>>>(x, xmean, xb);
  k_xavg<<<dim3(16, 16), 512, 0, stream>>>(xb, xavg);
  k_wtrans2<<<dim3(32, 8), 256, 0, stream>>>(qkv_w, wt, proj_w, pwt);
  k_dct_headw<<<dim3(16), 1024, 0, stream>>>(xmean, xavg, h1_w, h1_b, h2_w, h2_b,
                                             freq_w, dfeat, crow);
  k_gemm<0><<<dim3(12 * 128), 256, 0, stream>>>(xb, wt, qkv_b, freq_w, qbp, kbp, vtg, nullptr);
  k_attn<<<dim3(1024), 256, 0, stream>>>(qbp, kbp, vtg, crow, dfeat, freq_w, ao);
  k_gemm<1><<<dim3(4 * 128), 256, 0, stream>>>(ao, pwt, proj_b, freq_w, nullptr, nullptr, nullptr, out);
}